// Round 9
// baseline (243.760 us; speedup 1.0000x reference)
//
#include <hip/hip_runtime.h>

typedef unsigned int u32;
typedef unsigned short u16;
typedef unsigned char u8;
typedef __attribute__((ext_vector_type(8))) __bf16 bf16x8;
typedef __attribute__((ext_vector_type(4))) float f32x4;
typedef __attribute__((ext_vector_type(4))) int i32x4;

#define NB 16384
#define NM 4096
#define ND 512
#define NOUT 128
#define L2E 1.44269504088896340736f

// ws layout: x_ws fp8 [rb(256)][kg64(64)][row(64)][8B]   (8 MB)
//            s_ws fp8 [mb(32)][kg64(64)][m(128)][8B]     (2 MB, pre-scaled by -2*gamma*log2e)
//            hw_ws bf16 [slab=(mb*16+kg)][o(128)][8]     (1 MB)
// x2g[16384] = gamma*log2e*||x||^2 ; s2g[4096] = gamma*log2e*||s||^2  (fp32-exact)

#define WAITLG(N) do { asm volatile("s_waitcnt vmcnt(" #N ") lgkmcnt(0)" ::: "memory"); \
                       __builtin_amdgcn_sched_barrier(0); } while (0)
#define LGKM(N) do { asm volatile("s_waitcnt lgkmcnt(" #N ")" ::: "memory"); \
                     __builtin_amdgcn_sched_barrier(0); } while (0)
#define SB0() __builtin_amdgcn_sched_barrier(0)

// ---------- helpers ----------
__device__ __forceinline__ u16 f2bf(float f) {
  u32 u = __float_as_uint(f);
  u += 0x7FFFu + ((u >> 16) & 1u);   // RNE
  return (u16)(u >> 16);
}

// manual fp32 -> e4m3fn (RNE, flush |v|<2^-6 to 0; |v| <= ~15 here so no sat needed)
__device__ __forceinline__ u8 f2fp8(float f) {
  u32 u = __float_as_uint(f);
  u32 s = (u >> 24) & 0x80u;
  u32 au = u & 0x7FFFFFFFu;
  if (au < 0x3C800000u) return (u8)s;          // below min normal -> 0
  au += 0x000FFFFFu + ((au >> 20) & 1u);       // RNE to 3 mantissa bits
  u32 e = (au >> 23) - 120u;                   // rebias 127 -> 7
  u32 m = (au >> 20) & 7u;
  return (u8)(s | (e << 3) | m);
}

__device__ __forceinline__ void stage16(const void* g, void* l) {
  __builtin_amdgcn_global_load_lds((__attribute__((address_space(1))) void*)g,
                                   (__attribute__((address_space(3))) void*)l,
                                   16, 0, 0);
}

// compiler-invisible global loads: no forced compiler vmcnt before the consumer;
// my counted waits cover them (HW vmcnt counts asm loads too)
__device__ __forceinline__ bf16x8 ldg_b128(const void* p) {
  i32x4 r;
  asm volatile("global_load_dwordx4 %0, %1, off" : "=&v"(r) : "v"(p) : "memory");
  return __builtin_bit_cast(bf16x8, r);
}
__device__ __forceinline__ long long ldg_b64(const void* p) {
  long long r;
  asm volatile("global_load_dwordx2 %0, %1, off" : "=&v"(r) : "v"(p) : "memory");
  return r;
}

__device__ __forceinline__ uint4 pack8bf(float4 v0, float4 v1) {
  uint4 pk;
  pk.x = (u32)f2bf(v0.x) | ((u32)f2bf(v0.y) << 16);
  pk.y = (u32)f2bf(v0.z) | ((u32)f2bf(v0.w) << 16);
  pk.z = (u32)f2bf(v1.x) | ((u32)f2bf(v1.y) << 16);
  pk.w = (u32)f2bf(v1.z) | ((u32)f2bf(v1.w) << 16);
  return pk;
}

__device__ __forceinline__ uint2 pack8f8(float4 v0, float4 v1) {
  uint2 pk;
  pk.x = (u32)f2fp8(v0.x) | ((u32)f2fp8(v0.y) << 8) |
         ((u32)f2fp8(v0.z) << 16) | ((u32)f2fp8(v0.w) << 24);
  pk.y = (u32)f2fp8(v1.x) | ((u32)f2fp8(v1.y) << 8) |
         ((u32)f2fp8(v1.z) << 16) | ((u32)f2fp8(v1.w) << 24);
  return pk;
}

// ---------- merged prep ----------
// blocks [0,512): x tiles (fp8)   [512,640): support tiles (fp8, scaled)
// [640,672): head_w (bf16)        [672,736): zero d_out (64 blocks x 128 KB)
__global__ __launch_bounds__(256) void prep_all(const float* __restrict__ x,
                                                const float* __restrict__ s,
                                                const float* __restrict__ hw,
                                                const float* __restrict__ gamma_p,
                                                u8*  __restrict__ x_ws,
                                                u8*  __restrict__ s_ws,
                                                u16* __restrict__ hw_ws,
                                                float* __restrict__ x2g,
                                                float* __restrict__ s2g,
                                                float* __restrict__ out) {
  __shared__ uint2 t8[2048];       // 16 KB (x/s transpose, XOR-swizzled)
  __shared__ uint4 t16[2048];      // 32 KB (hw transpose)
  const int tid = threadIdx.x, bid = blockIdx.x;
  const int lane = tid & 63, w = tid >> 6;

  if (bid < 640) {
    const bool isx = bid < 512;
    const int blk = isx ? bid : (bid - 512);
    const float* src_m = isx ? x : s;
    u8*    dst_ws = isx ? x_ws : s_ws;
    float* sq_out = isx ? x2g : s2g;
    const float gl   = gamma_p[0] * L2E;
    const float cmul = isx ? 1.0f : (-2.0f * gl);
    const int big  = isx ? (blk >> 1) : (blk >> 2);
    const int roff = isx ? ((blk & 1) * 32) : ((blk & 3) * 32);
    const int rows = isx ? 64 : 128;

    #pragma unroll
    for (int p = 0; p < 8; ++p) {
      const int row = p * 4 + w;                      // local row 0..31
      const float* src = src_m + (size_t)(blk * 32 + row) * ND + lane * 8;
      float4 v0 = *(const float4*)src;
      float4 v1 = *(const float4*)(src + 4);
      float ss = v0.x*v0.x + v0.y*v0.y + v0.z*v0.z + v0.w*v0.w
               + v1.x*v1.x + v1.y*v1.y + v1.z*v1.z + v1.w*v1.w;
      #pragma unroll
      for (int off = 32; off > 0; off >>= 1) ss += __shfl_down(ss, off);
      if (lane == 0) sq_out[blk * 32 + row] = gl * ss;
      v0.x *= cmul; v0.y *= cmul; v0.z *= cmul; v0.w *= cmul;
      v1.x *= cmul; v1.y *= cmul; v1.z *= cmul; v1.w *= cmul;
      t8[lane * 32 + ((row + lane) & 31)] = pack8f8(v0, v1);   // kg = lane
    }
    __syncthreads();
    #pragma unroll
    for (int p = 0; p < 8; ++p) {
      const int kg = p * 8 + (tid >> 5);
      const int row = tid & 31;
      uint2 pk = t8[kg * 32 + ((row + kg) & 31)];
      *(uint2*)&dst_ws[(((size_t)(big * 64 + kg)) * rows + roff + row) * 8] = pk;
    }
  } else if (bid < 672) {
    // ---- head_w: m-chunk of 128 (bf16) ----
    const int blk = bid - 640;
    #pragma unroll
    for (int p = 0; p < 8; ++p) {
      const int o = p * 16 + (tid >> 4);
      const int kg = tid & 15;
      const float* src = hw + (size_t)o * NM + blk * 128 + kg * 8;
      float4 v0 = *(const float4*)src;
      float4 v1 = *(const float4*)(src + 4);
      t16[o * 16 + ((kg + o) & 15)] = pack8bf(v0, v1);
    }
    __syncthreads();
    #pragma unroll
    for (int it = 0; it < 8; ++it) {
      const int kg = it * 2 + (tid >> 7);
      const int o = tid & 127;
      uint4 pk = t16[o * 16 + ((kg + o) & 15)];
      *(uint4*)&hw_ws[(((size_t)(blk * 16 + kg)) * 128 + o) * 8] = pk;
    }
  } else {
    // ---- zero d_out: 64 blocks x 128 KB ----
    float4* o4 = (float4*)out;
    const float4 z = {0.f, 0.f, 0.f, 0.f};
    size_t base = (size_t)(bid - 672) * 8192 + tid;
    #pragma unroll 8
    for (int i = 0; i < 32; ++i) o4[base + (size_t)i * 256] = z;
  }
}

// ---------- main fused kernel ----------
// R9 = R5 pipeline with X served from L2 instead of LDS -> LDS 48K static
// (ring 4x8K @0, Ks 16K @32768) -> 3 blocks/CU = 3 waves/SIMD (was 2).
// Rationale: R5/R8 pinned at ~37% MfmaUtil regardless of barrier count (R8) or
// slot size (R6) — wave serial path is latency-bound at 2 waves/SIMD; the only
// untried axis is occupancy, blocked by the 80K LDS. X reuse is 16x over 32KB
// (per-XCD X working set ~4MB ~ L2), so A-frags come from L2 via asm
// global_load_dwordx2 (addresses mt-independent: xb_r + (gN&7)*4096 + k2*2048),
// issued one slot ahead into the aF parity buffer like the old LDS reads.
// a2h hoist dropped (per-slot a2 b128 reads, compiler-ordered) to keep VGPR<=128
// (R7 lesson: allocator pins at 128 and spills beyond ~130 demand).
// Per-slot vm FIFO: [s2v@g0][aF x4][stage x2][b2 x4 @even]. End-of-slot WAITLG
// drains through aF (consumed right after the barrier), leaves stage(t+3)+b2:
//   steady: even N=6, odd N=2 (stage lead-3 and b2 lead-2 stay in flight);
//   mt0: N=2 (no b2) except grp6 N=6;  mt7: {6,2,6,2,6,0,0,0}.
// Ring WAR: slot t stages buf (t+3)&3, last read during slot t-2, barrier at
// end of t-2 precedes the issue ✓. Epilogue barrier is lgkm-only (stages for
// the next mt stay in flight).
__global__ __launch_bounds__(256, 2)
void rbf_fused(const u8* __restrict__ x_ws, const u8* __restrict__ s_ws,
               const u16* __restrict__ hw_ws, const float* __restrict__ x2g,
               const float* __restrict__ s2g, const float* __restrict__ head_b,
               const float* __restrict__ scale_p, const float* __restrict__ shift_p,
               float* __restrict__ out)
{
  __shared__ __align__(16) char smem[49152];   // 48 KB static: ring 32K + Ks 16K

  const int tid  = threadIdx.x;
  const int w    = tid >> 6;
  const int lane = tid & 63;
  const int quad = lane >> 4;
  const int l16  = lane & 15;
  const int wr   = w & 1;    // row half (32 rows)
  const int wc   = w >> 1;   // m / out-col half (64)
  const int xcd  = blockIdx.x & 7;
  const int rb   = (blockIdx.x >> 3) * 2 + (xcd & 1);
  const int half = xcd >> 1;
  const int b0   = rb * 64;

  const float vscale = scale_p[0];
  const float vshift = shift_p[0];

  const u8* xsrc = x_ws + (size_t)rb * 32768;
  const u8* ssrc = s_ws + (size_t)(half * 8) * 65536;

  // per-lane A-frag base addresses (r=0,1); slot offset = (gN&7)*4096 + k2*2048
  const u8* xb0 = xsrc + quad * 512 + (wr * 32 + l16) * 8;
  const u8* xb1 = xsrc + quad * 512 + (wr * 32 + 16 + l16) * 8;

  auto stage_grp = [&](int mt_s, int grp_s) {
    const u8* sp = ssrc + (size_t)mt_s * 65536 + grp_s * 8192;
    char* dp = smem + (grp_s & 3) * 8192;
    stage16(sp + tid * 16, dp + tid * 16);
    stage16(sp + 4096 + tid * 16, dp + 4096 + tid * 16);
  };

  // fragment register double-buffers
  long long aF[2][2][2];     // [parity][k2][r]  (asm global loads)
  long long bF[2][2][4];     // [parity][k2][c]  (LDS reads)
  bf16x8 b2[2][4];           // gemm2 B, asm-issued 2 slots ahead
  bf16x8 a2[2];              // Ks slab, read per even slot

  // ---- prologue: x2v, S tiles 0..2, aF(slot0); full drain ----
  f32x4 x2v[2];
  #pragma unroll
  for (int r = 0; r < 2; ++r)
    x2v[r] = *(const f32x4*)&x2g[b0 + wr * 32 + r * 16 + quad * 4];
  SB0();
  stage_grp(0, 0); SB0();
  stage_grp(0, 1); SB0();
  stage_grp(0, 2); SB0();
  aF[0][0][0] = ldg_b64(xb0);
  aF[0][0][1] = ldg_b64(xb1);
  aF[0][1][0] = ldg_b64(xb0 + 2048);
  aF[0][1][1] = ldg_b64(xb1 + 2048);
  WAITLG(0);
  __builtin_amdgcn_s_barrier();
  SB0();

  // ---- bF reads for slot 0 -> parity 0 (buf 0) ----
  #pragma unroll
  for (int k2 = 0; k2 < 2; ++k2)
    #pragma unroll
    for (int c = 0; c < 4; ++c)
      bF[0][k2][c] = *(const long long*)(smem +
                       ((k2 * 4 + quad) * 128 + wc * 64 + c * 16 + l16) * 8);
  LGKM(0);
  __builtin_amdgcn_s_barrier();   // all waves' buf-0 reads done before slot-1's stage->buf0
  SB0();

  const f32x4 zf = {0.f, 0.f, 0.f, 0.f};
  f32x4 acc_xs[2][4];
  f32x4 acc_out[2][4];
  #pragma unroll
  for (int r = 0; r < 2; ++r)
    #pragma unroll
    for (int c = 0; c < 4; ++c) { acc_xs[r][c] = zf; acc_out[r][c] = zf; }

  #pragma unroll 1
  for (int mt = 0; mt < 8; ++mt) {
    const int mtg = half * 8 + mt;
    float s2v[4];

    #pragma unroll
    for (int grp = 0; grp < 8; ++grp) {
      const int p  = grp & 1;
      const int pn = p ^ 1;
      const int gN = grp + 1;                 // next slot
      const bool doRd = !(mt == 7 && grp == 7);

      // ---- slot top: s2v | aF(gN) | stage(t+3) | b2(t+2) — FIFO order pinned ----
      if (grp == 0) {
        #pragma unroll
        for (int c = 0; c < 4; ++c)
          s2v[c] = s2g[mtg * 128 + wc * 64 + c * 16 + l16];
        SB0();
      }
      if (doRd) {
        const int xo = (gN & 7) * 4096;
        aF[pn][0][0] = ldg_b64(xb0 + xo);
        aF[pn][0][1] = ldg_b64(xb1 + xo);
        aF[pn][1][0] = ldg_b64(xb0 + xo + 2048);
        aF[pn][1][1] = ldg_b64(xb1 + xo + 2048);
      }
      SB0();
      if (grp <= 4)     stage_grp(mt, grp + 3);
      else if (mt < 7)  stage_grp(mt + 1, grp - 5);
      SB0();
      if ((grp & 1) == 0 && ((grp < 6 && mt >= 1) || (grp == 6 && mt <= 6))) {
        const int um = mt + (grp == 6);
        const int ks = ((grp >> 1) + 1) & 3;
        const size_t sb = (size_t)((half * 8 + um - 1) * 16 + ks * 4 + quad);
        #pragma unroll
        for (int c = 0; c < 4; ++c)
          b2[((grp >> 1) + 1) & 1][c] = ldg_b128(hw_ws + (sb * 128 + wc * 64 + c * 16 + l16) * 8);
      }
      SB0();

      // ---- MFMA chunk 1: k2=0 (8 fp8) | bF kc0 reads for gN (+a2 on even) ----
      __builtin_amdgcn_s_setprio(1);
      #pragma unroll
      for (int r = 0; r < 2; ++r)
        #pragma unroll
        for (int c = 0; c < 4; ++c)
          acc_xs[r][c] = __builtin_amdgcn_mfma_f32_16x16x32_fp8_fp8(
              aF[p][0][r], bF[p][0][c], acc_xs[r][c], 0, 0, 0);
      __builtin_amdgcn_s_setprio(0);
      SB0();
      if (doRd) {
        #pragma unroll
        for (int c = 0; c < 4; ++c)
          bF[pn][0][c] = *(const long long*)(smem + (gN & 3) * 8192 +
              ((0 * 4 + quad) * 128 + wc * 64 + c * 16 + l16) * 8);
      }
      if (mt > 0 && (grp & 1) == 0) {
        const int kg = (grp >> 1) * 4 + quad;
        #pragma unroll
        for (int r = 0; r < 2; ++r)
          a2[r] = *(const bf16x8*)(smem + 32768 + (kg * 64 + wr * 32 + r * 16 + l16) * 16);
      }
      SB0();

      // ---- MFMA chunk 2: k2=1 (8 fp8) | bF kc1 reads for gN ----
      __builtin_amdgcn_s_setprio(1);
      #pragma unroll
      for (int r = 0; r < 2; ++r)
        #pragma unroll
        for (int c = 0; c < 4; ++c)
          acc_xs[r][c] = __builtin_amdgcn_mfma_f32_16x16x32_fp8_fp8(
              aF[p][1][r], bF[p][1][c], acc_xs[r][c], 0, 0, 0);
      __builtin_amdgcn_s_setprio(0);
      SB0();
      if (doRd) {
        #pragma unroll
        for (int c = 0; c < 4; ++c)
          bF[pn][1][c] = *(const long long*)(smem + (gN & 3) * 8192 +
              ((1 * 4 + quad) * 128 + wc * 64 + c * 16 + l16) * 8);
      }
      SB0();

      // ---- gemm2 (even, mt>0): a2 dep compiler-ordered; b2 from regs ----
      if (mt > 0 && (grp & 1) == 0) {
        __builtin_amdgcn_s_setprio(1);
        #pragma unroll
        for (int r = 0; r < 2; ++r)
          #pragma unroll
          for (int c = 0; c < 4; ++c)
            acc_out[r][c] = __builtin_amdgcn_mfma_f32_16x16x32_bf16(
                a2[r], b2[(grp >> 1) & 1][c], acc_out[r][c], 0, 0, 0);
        __builtin_amdgcn_s_setprio(0);
      }
      SB0();

      // ---- end-of-slot counted wait (drain aF(gN); keep stage(t+3)+b2) ----
      if (mt == 0)      { if (grp == 6) WAITLG(6); else WAITLG(2); }
      else if (mt < 7)  { if ((grp & 1) == 0) WAITLG(6); else WAITLG(2); }
      else {
        if (grp == 0 || grp == 2 || grp == 4)      WAITLG(6);
        else if (grp == 1 || grp == 3)             WAITLG(2);
        else                                       WAITLG(0);
      }
      __builtin_amdgcn_s_barrier();
      SB0();
    }

    // ---- epilogue: t = acc + x2g + s2g ; k = min(exp2(-t),1) -> bf16 Ks ----
    {
      #pragma unroll
      for (int r = 0; r < 2; ++r)
        #pragma unroll
        for (int c = 0; c < 4; ++c) {
          const int cl = wc * 64 + c * 16 + l16;     // m-col 0..127
          char* kbase = smem + 32768 + (cl >> 3) * 1024 + (cl & 7) * 2;
          #pragma unroll
          for (int i = 0; i < 4; ++i) {
            const int row = wr * 32 + r * 16 + quad * 4 + i;
            const float t = acc_xs[r][c][i] + x2v[r][i] + s2v[c];
            float kv = __builtin_amdgcn_exp2f(-t);
            kv = fminf(kv, 1.0f);
            *(u16*)(kbase + row * 16) = (u16)(__float_as_uint(kv) >> 16);
            acc_xs[r][c][i] = 0.0f;
          }
        }
    }
    // lgkm-only barrier: Ks writes ordered before next mt's a2 reads; in-flight
    // stages stay in flight
    LGKM(0);
    __builtin_amdgcn_s_barrier();
    SB0();
  }

  // ---- drained GEMM2 for the last mtile (Ks(7)) ----
  #pragma unroll
  for (int ks = 0; ks < 4; ++ks) {
    const int kg = ks * 4 + quad;
    const size_t sb = (size_t)((half * 8 + 7) * 16 + kg);
    bf16x8 bb[4], aa[2];
    #pragma unroll
    for (int c = 0; c < 4; ++c)
      bb[c] = *(const bf16x8*)(hw_ws + (sb * 128 + wc * 64 + c * 16 + l16) * 8);
    #pragma unroll
    for (int r = 0; r < 2; ++r)
      aa[r] = *(const bf16x8*)(smem + 32768 + (kg * 64 + wr * 32 + r * 16 + l16) * 16);
    #pragma unroll
    for (int r = 0; r < 2; ++r)
      #pragma unroll
      for (int c = 0; c < 4; ++c)
        acc_out[r][c] = __builtin_amdgcn_mfma_f32_16x16x32_bf16(aa[r], bb[c], acc_out[r][c], 0, 0, 0);
  }

  // ---- final: atomic-accumulate scale*acc (+ bias/shift once, by half==0 blocks) ----
  float addv[4];
  #pragma unroll
  for (int c = 0; c < 4; ++c) {
    const int col = wc * 64 + c * 16 + l16;
    addv[c] = (half == 0) ? (vscale * head_b[col] + vshift) : 0.0f;
  }
  #pragma unroll
  for (int r = 0; r < 2; ++r)
    #pragma unroll
    for (int c = 0; c < 4; ++c) {
      const int col = wc * 64 + c * 16 + l16;
      #pragma unroll
      for (int i = 0; i < 4; ++i) {
        const int row = b0 + wr * 32 + r * 16 + quad * 4 + i;
        atomicAdd(&out[(size_t)row * NOUT + col], vscale * acc_out[r][c][i] + addv[c]);
      }
    }
}

// ---------- launch ----------
extern "C" void kernel_launch(void* const* d_in, const int* in_sizes, int n_in,
                              void* d_out, int out_size, void* d_ws, size_t ws_size,
                              hipStream_t stream) {
  const float* x       = (const float*)d_in[0];
  const float* support = (const float*)d_in[1];
  const float* gamma   = (const float*)d_in[2];
  const float* head_w  = (const float*)d_in[3];
  const float* head_b  = (const float*)d_in[4];
  const float* scale   = (const float*)d_in[5];
  const float* shift   = (const float*)d_in[6];
  float* out = (float*)d_out;

  char* w = (char*)d_ws;
  u8*    x_ws  = (u8*)(w);                        //  8,388,608 B
  u8*    s_ws  = (u8*)(w + 8388608);              //  2,097,152 B
  u16*   hw_ws = (u16*)(w + 10485760);            //  1,048,576 B
  float* x2g   = (float*)(w + 11534336);          //     65,536 B
  float* s2g   = (float*)(w + 11599872);          //     16,384 B

  prep_all<<<736, 256, 0, stream>>>(x, support, head_w, gamma,
                                    x_ws, s_ws, hw_ws, x2g, s2g, out);
  rbf_fused<<<1024, 256, 0, stream>>>(x_ws, s_ws, hw_ws, x2g, s2g,
                                      head_b, scale, shift, out);
}

// Round 11
// 187.513 us; speedup vs baseline: 1.3000x; 1.3000x over previous
//
#include <hip/hip_runtime.h>

typedef unsigned int u32;
typedef unsigned short u16;
typedef unsigned char u8;
typedef __attribute__((ext_vector_type(8))) __bf16 bf16x8;
typedef __attribute__((ext_vector_type(4))) float f32x4;
typedef __attribute__((ext_vector_type(4))) int i32x4;

#define NB 16384
#define NM 4096
#define ND 512
#define NOUT 128
#define L2E 1.44269504088896340736f

// ws layout: x_ws fp8 [rb64(256)][kg64(64)][row(64)][8B]  (8 MB)
//            s_ws fp8 [mb(32)][kg64(64)][m(128)][8B]      (2 MB, pre-scaled by -2*gamma*log2e)
//            hw_ws bf16 [slab=(mb*16+kg)][o(128)][8]      (1 MB)
// x2g[16384] = gamma*log2e*||x||^2 ; s2g[4096] = gamma*log2e*||s||^2  (fp32-exact)

#define WAITLG(N) do { asm volatile("s_waitcnt vmcnt(" #N ") lgkmcnt(0)" ::: "memory"); \
                       __builtin_amdgcn_sched_barrier(0); } while (0)
#define LGKM(N) do { asm volatile("s_waitcnt lgkmcnt(" #N ")" ::: "memory"); \
                     __builtin_amdgcn_sched_barrier(0); } while (0)
#define SB0() __builtin_amdgcn_sched_barrier(0)

// ---------- helpers ----------
__device__ __forceinline__ u16 f2bf(float f) {
  u32 u = __float_as_uint(f);
  u += 0x7FFFu + ((u >> 16) & 1u);   // RNE
  return (u16)(u >> 16);
}

// manual fp32 -> e4m3fn (RNE, flush |v|<2^-6 to 0; |v| <= ~15 here so no sat needed)
__device__ __forceinline__ u8 f2fp8(float f) {
  u32 u = __float_as_uint(f);
  u32 s = (u >> 24) & 0x80u;
  u32 au = u & 0x7FFFFFFFu;
  if (au < 0x3C800000u) return (u8)s;          // below min normal -> 0
  au += 0x000FFFFFu + ((au >> 20) & 1u);       // RNE to 3 mantissa bits
  u32 e = (au >> 23) - 120u;                   // rebias 127 -> 7
  u32 m = (au >> 20) & 7u;
  return (u8)(s | (e << 3) | m);
}

__device__ __forceinline__ void stage16(const void* g, void* l) {
  __builtin_amdgcn_global_load_lds((__attribute__((address_space(1))) void*)g,
                                   (__attribute__((address_space(3))) void*)l,
                                   16, 0, 0);
}

// compiler-invisible b128 global load: no forced compiler vmcnt before the
// consumer; my end-of-slot WAITLG(0) covers it (HW vmcnt counts asm loads)
__device__ __forceinline__ bf16x8 ldg_b128(const void* p) {
  i32x4 r;
  asm volatile("global_load_dwordx4 %0, %1, off" : "=&v"(r) : "v"(p) : "memory");
  return __builtin_bit_cast(bf16x8, r);
}

__device__ __forceinline__ uint4 pack8bf(float4 v0, float4 v1) {
  uint4 pk;
  pk.x = (u32)f2bf(v0.x) | ((u32)f2bf(v0.y) << 16);
  pk.y = (u32)f2bf(v0.z) | ((u32)f2bf(v0.w) << 16);
  pk.z = (u32)f2bf(v1.x) | ((u32)f2bf(v1.y) << 16);
  pk.w = (u32)f2bf(v1.z) | ((u32)f2bf(v1.w) << 16);
  return pk;
}

__device__ __forceinline__ uint2 pack8f8(float4 v0, float4 v1) {
  uint2 pk;
  pk.x = (u32)f2fp8(v0.x) | ((u32)f2fp8(v0.y) << 8) |
         ((u32)f2fp8(v0.z) << 16) | ((u32)f2fp8(v0.w) << 24);
  pk.y = (u32)f2fp8(v1.x) | ((u32)f2fp8(v1.y) << 8) |
         ((u32)f2fp8(v1.z) << 16) | ((u32)f2fp8(v1.w) << 24);
  return pk;
}

// ---------- merged prep ----------
// blocks [0,512): x tiles (fp8)   [512,640): support tiles (fp8, scaled)
// [640,672): head_w (bf16)        [672,736): zero d_out (64 blocks x 128 KB)
__global__ __launch_bounds__(256) void prep_all(const float* __restrict__ x,
                                                const float* __restrict__ s,
                                                const float* __restrict__ hw,
                                                const float* __restrict__ gamma_p,
                                                u8*  __restrict__ x_ws,
                                                u8*  __restrict__ s_ws,
                                                u16* __restrict__ hw_ws,
                                                float* __restrict__ x2g,
                                                float* __restrict__ s2g,
                                                float* __restrict__ out) {
  __shared__ uint2 t8[2048];       // 16 KB (x/s transpose, XOR-swizzled)
  __shared__ uint4 t16[2048];      // 32 KB (hw transpose)
  const int tid = threadIdx.x, bid = blockIdx.x;
  const int lane = tid & 63, w = tid >> 6;

  if (bid < 640) {
    const bool isx = bid < 512;
    const int blk = isx ? bid : (bid - 512);
    const float* src_m = isx ? x : s;
    u8*    dst_ws = isx ? x_ws : s_ws;
    float* sq_out = isx ? x2g : s2g;
    const float gl   = gamma_p[0] * L2E;
    const float cmul = isx ? 1.0f : (-2.0f * gl);
    const int big  = isx ? (blk >> 1) : (blk >> 2);
    const int roff = isx ? ((blk & 1) * 32) : ((blk & 3) * 32);
    const int rows = isx ? 64 : 128;

    #pragma unroll
    for (int p = 0; p < 8; ++p) {
      const int row = p * 4 + w;                      // local row 0..31
      const float* src = src_m + (size_t)(blk * 32 + row) * ND + lane * 8;
      float4 v0 = *(const float4*)src;
      float4 v1 = *(const float4*)(src + 4);
      float ss = v0.x*v0.x + v0.y*v0.y + v0.z*v0.z + v0.w*v0.w
               + v1.x*v1.x + v1.y*v1.y + v1.z*v1.z + v1.w*v1.w;
      #pragma unroll
      for (int off = 32; off > 0; off >>= 1) ss += __shfl_down(ss, off);
      if (lane == 0) sq_out[blk * 32 + row] = gl * ss;
      v0.x *= cmul; v0.y *= cmul; v0.z *= cmul; v0.w *= cmul;
      v1.x *= cmul; v1.y *= cmul; v1.z *= cmul; v1.w *= cmul;
      t8[lane * 32 + ((row + lane) & 31)] = pack8f8(v0, v1);   // kg = lane
    }
    __syncthreads();
    #pragma unroll
    for (int p = 0; p < 8; ++p) {
      const int kg = p * 8 + (tid >> 5);
      const int row = tid & 31;
      uint2 pk = t8[kg * 32 + ((row + kg) & 31)];
      *(uint2*)&dst_ws[(((size_t)(big * 64 + kg)) * rows + roff + row) * 8] = pk;
    }
  } else if (bid < 672) {
    // ---- head_w: m-chunk of 128 (bf16) ----
    const int blk = bid - 640;
    #pragma unroll
    for (int p = 0; p < 8; ++p) {
      const int o = p * 16 + (tid >> 4);
      const int kg = tid & 15;
      const float* src = hw + (size_t)o * NM + blk * 128 + kg * 8;
      float4 v0 = *(const float4*)src;
      float4 v1 = *(const float4*)(src + 4);
      t16[o * 16 + ((kg + o) & 15)] = pack8bf(v0, v1);
    }
    __syncthreads();
    #pragma unroll
    for (int it = 0; it < 8; ++it) {
      const int kg = it * 2 + (tid >> 7);
      const int o = tid & 127;
      uint4 pk = t16[o * 16 + ((kg + o) & 15)];
      *(uint4*)&hw_ws[(((size_t)(blk * 16 + kg)) * 128 + o) * 8] = pk;
    }
  } else {
    // ---- zero d_out: 64 blocks x 128 KB ----
    float4* o4 = (float4*)out;
    const float4 z = {0.f, 0.f, 0.f, 0.f};
    size_t base = (size_t)(bid - 672) * 8192 + tid;
    #pragma unroll 8
    for (int i = 0; i < 32; ++i) o4[base + (size_t)i * 256] = z;
  }
}

// ---------- main fused kernel ----------
// R11 = R10 resubmitted (R10 died to a container/infra failure, not a kernel
// fault: all barriers control-uniform, all addresses bounds-audited).
// OCCUPANCY round. 32-row blocks (grid 2048 = 512 rb x 4 M-quarters),
// 256 thr / 4 waves, wave tile 16x64 (wr=w&1 row-half, wc=w>>1 col-half).
// LDS 40960 STATIC: X 16K @0 (resident; R9's X-from-L2 thrashed the 4MB L2),
// S dbuf 2x8K @16384, Ks 8K @32768  ->  4 blocks/CU = 16 waves/CU = 4 w/SIMD.
// Model: per-wave MFMA demand ~20% of slot; pipe busy ~ 1-(1-p)^n: n=2 -> 36%
// (matches R5/R8's measured 37%); n=4 -> ~59%. Simple 2-phase slot (reads at
// use, end-of-slot WAITLG(0)+barrier): per-wave drain is covered by 4-way TLP
// (m97 regime). b2 via asm loads at odd slots (invisible to compiler waitcnt
// pass -> no forced mid-slot drain; guaranteed by the previous slot's
// WAITLG(0)). launch_bounds(256,4) caps VGPR at 128; demand ~100 (R7 lesson:
// stay under the 128 pin).
// X LDS [kg64][row32][8B]; aF addr = (kg*32 + wr*16 + l16)*8, kg=kc*4+quad.
// Ks [colgrp16][row32][col8]x2B; a2 = b128 @ colgrp*512 + (wr*16+l16)*16.
__global__ __launch_bounds__(256, 4)
void rbf_fused(const u8* __restrict__ x_ws, const u8* __restrict__ s_ws,
               const u16* __restrict__ hw_ws, const float* __restrict__ x2g,
               const float* __restrict__ s2g, const float* __restrict__ head_b,
               const float* __restrict__ scale_p, const float* __restrict__ shift_p,
               float* __restrict__ out)
{
  __shared__ __align__(16) char smem[40960];   // X 16K | S 2x8K | Ks 8K

  const int tid  = threadIdx.x;
  const int w    = tid >> 6;
  const int lane = tid & 63;
  const int quad = lane >> 4;
  const int l16  = lane & 15;
  const int wr   = w & 1;    // 16-row half
  const int wc   = w >> 1;   // 64-col half
  const int xcd  = blockIdx.x & 7;
  const int rb   = (blockIdx.x >> 3) * 2 + (xcd & 1);   // [0,512)
  const int half = xcd >> 1;                            // [0,4)
  const int b0   = rb * 32;

  const float vscale = scale_p[0];
  const float vshift = shift_p[0];

  const u8* xsrc = x_ws + (size_t)(rb >> 1) * 32768;
  const int roff = (rb & 1) * 256;                      // 32-row offset * 8B
  const u8* ssrc = s_ws + (size_t)(half * 8) * 65536;

  auto stage_tile = [&](int mt_s, int grp_s, int buf) {
    const u8* sp = ssrc + (size_t)mt_s * 65536 + grp_s * 8192;
    char* dp = smem + 16384 + buf * 8192;
    stage16(sp + tid * 16, dp + tid * 16);
    stage16(sp + 4096 + tid * 16, dp + 4096 + tid * 16);
  };

  // ---- prologue: x2v, X->LDS (16KB, 4 calls), S tile(0,0)->buf0 ----
  f32x4 x2v = *(const f32x4*)&x2g[b0 + wr * 16 + quad * 4];
  SB0();
  #pragma unroll
  for (int i = 0; i < 4; ++i) {
    // kg = i*16 + (tid>>4); 16B chunk = rows 2*(tid&15),+1 ; dst linear == kg*256+row*8
    const u8* src = xsrc + (size_t)(i * 16 + (tid >> 4)) * 512 + roff + (tid & 15) * 16;
    stage16(src, smem + i * 4096 + tid * 16);
  }
  SB0();
  stage_tile(0, 0, 0);
  WAITLG(0);
  __builtin_amdgcn_s_barrier();
  SB0();

  const f32x4 zf = {0.f, 0.f, 0.f, 0.f};
  f32x4 acc_xs[4], acc_out[4];
  #pragma unroll
  for (int c = 0; c < 4; ++c) { acc_xs[c] = zf; acc_out[c] = zf; }

  bf16x8 b2[4];     // gemm2 B: asm-loaded at odd slots, consumed at next even slot

  #pragma unroll 1
  for (int mt = 0; mt < 8; ++mt) {
    const int mtg = half * 8 + mt;
    float s2v[4];

    #pragma unroll
    for (int grp = 0; grp < 8; ++grp) {
      const int buf = grp & 1;

      // ---- slot top: s2v@g0 | stage next tile -> buf^1 | b2 (odd) ----
      if (grp == 0) {
        #pragma unroll
        for (int c = 0; c < 4; ++c)
          s2v[c] = s2g[mtg * 128 + wc * 64 + c * 16 + l16];
        SB0();
      }
      if (!(mt == 7 && grp == 7)) {
        if (grp < 7) stage_tile(mt, grp + 1, buf ^ 1);
        else         stage_tile(mt + 1, 0, buf ^ 1);
      }
      SB0();
      if ((grp & 1) == 1 && ((grp < 7) ? (mt >= 1) : (mt <= 6))) {
        const int ks = (grp < 7) ? ((grp + 1) >> 1) : 0;
        const int sm = (grp < 7) ? (mtg - 1) : mtg;
        const size_t sb = (size_t)(sm * 16 + ks * 4 + quad);
        #pragma unroll
        for (int c = 0; c < 4; ++c)
          b2[c] = ldg_b128(hw_ws + (sb * 128 + wc * 64 + c * 16 + l16) * 8);
      }
      SB0();

      // ---- fragment reads (this slot) ----
      long long aF[2], bF[2][4];
      #pragma unroll
      for (int k2 = 0; k2 < 2; ++k2) {
        const int kc = grp * 2 + k2;
        aF[k2] = *(const long long*)(smem + ((kc * 4 + quad) * 32 + wr * 16 + l16) * 8);
        #pragma unroll
        for (int c = 0; c < 4; ++c)
          bF[k2][c] = *(const long long*)(smem + 16384 + buf * 8192 +
                        ((k2 * 4 + quad) * 128 + wc * 64 + c * 16 + l16) * 8);
      }
      bf16x8 a2;
      if (mt > 0 && (grp & 1) == 0)
        a2 = *(const bf16x8*)(smem + 32768 + ((grp >> 1) * 4 + quad) * 512 +
                              (wr * 16 + l16) * 16);
      LGKM(0);

      // ---- MFMA ----
      __builtin_amdgcn_s_setprio(1);
      #pragma unroll
      for (int k2 = 0; k2 < 2; ++k2)
        #pragma unroll
        for (int c = 0; c < 4; ++c)
          acc_xs[c] = __builtin_amdgcn_mfma_f32_16x16x32_fp8_fp8(
              aF[k2], bF[k2][c], acc_xs[c], 0, 0, 0);
      if (mt > 0 && (grp & 1) == 0) {
        #pragma unroll
        for (int c = 0; c < 4; ++c)
          acc_out[c] = __builtin_amdgcn_mfma_f32_16x16x32_bf16(a2, b2[c], acc_out[c], 0, 0, 0);
      }
      __builtin_amdgcn_s_setprio(0);

      // ---- end of slot: drain stage (lead-1) + publish ----
      WAITLG(0);
      __builtin_amdgcn_s_barrier();
      SB0();
    }

    // ---- epilogue: t = acc + x2g + s2g ; k = min(exp2(-t),1) -> bf16 Ks ----
    #pragma unroll
    for (int c = 0; c < 4; ++c) {
      const int cl = wc * 64 + c * 16 + l16;       // m-col 0..127
      char* kbase = smem + 32768 + (cl >> 3) * 512 + (cl & 7) * 2;
      #pragma unroll
      for (int i = 0; i < 4; ++i) {
        const int row = wr * 16 + quad * 4 + i;
        const float t = acc_xs[c][i] + x2v[i] + s2v[c];
        float kv = __builtin_amdgcn_exp2f(-t);
        kv = fminf(kv, 1.0f);
        *(u16*)(kbase + row * 16) = (u16)(__float_as_uint(kv) >> 16);
        acc_xs[c][i] = 0.0f;
      }
    }
    // lgkm-only barrier: Ks writes ordered before next mt's a2 reads; the
    // in-flight stage for (mt+1,0) stays in flight
    LGKM(0);
    __builtin_amdgcn_s_barrier();
    SB0();
  }

  // ---- drained GEMM2 for the last mtile (Ks(7)) ----
  #pragma unroll
  for (int ks = 0; ks < 4; ++ks) {
    const size_t sb = (size_t)((half * 8 + 7) * 16 + ks * 4 + quad);
    bf16x8 bb[4];
    #pragma unroll
    for (int c = 0; c < 4; ++c)
      bb[c] = *(const bf16x8*)(hw_ws + (sb * 128 + wc * 64 + c * 16 + l16) * 8);
    bf16x8 aa = *(const bf16x8*)(smem + 32768 + (ks * 4 + quad) * 512 +
                                 (wr * 16 + l16) * 16);
    #pragma unroll
    for (int c = 0; c < 4; ++c)
      acc_out[c] = __builtin_amdgcn_mfma_f32_16x16x32_bf16(aa, bb[c], acc_out[c], 0, 0, 0);
  }

  // ---- final: atomic-accumulate scale*acc (+ bias/shift once, by half==0 blocks) ----
  float addv[4];
  #pragma unroll
  for (int c = 0; c < 4; ++c) {
    const int col = wc * 64 + c * 16 + l16;
    addv[c] = (half == 0) ? (vscale * head_b[col] + vshift) : 0.0f;
  }
  #pragma unroll
  for (int c = 0; c < 4; ++c) {
    const int col = wc * 64 + c * 16 + l16;
    #pragma unroll
    for (int i = 0; i < 4; ++i) {
      const int row = b0 + wr * 16 + quad * 4 + i;
      atomicAdd(&out[(size_t)row * NOUT + col], vscale * acc_out[c][i] + addv[c]);
    }
  }
}

// ---------- launch ----------
extern "C" void kernel_launch(void* const* d_in, const int* in_sizes, int n_in,
                              void* d_out, int out_size, void* d_ws, size_t ws_size,
                              hipStream_t stream) {
  const float* x       = (const float*)d_in[0];
  const float* support = (const float*)d_in[1];
  const float* gamma   = (const float*)d_in[2];
  const float* head_w  = (const float*)d_in[3];
  const float* head_b  = (const float*)d_in[4];
  const float* scale   = (const float*)d_in[5];
  const float* shift   = (const float*)d_in[6];
  float* out = (float*)d_out;

  char* w = (char*)d_ws;
  u8*    x_ws  = (u8*)(w);                        //  8,388,608 B
  u8*    s_ws  = (u8*)(w + 8388608);              //  2,097,152 B
  u16*   hw_ws = (u16*)(w + 10485760);            //  1,048,576 B
  float* x2g   = (float*)(w + 11534336);          //     65,536 B
  float* s2g   = (float*)(w + 11599872);          //     16,384 B

  prep_all<<<736, 256, 0, stream>>>(x, support, head_w, gamma,
                                    x_ws, s_ws, hw_ws, x2g, s2g, out);
  rbf_fused<<<2048, 256, 0, stream>>>(x_ws, s_ws, hw_ws, x2g, s2g,
                                      head_b, scale, shift, out);
}